// Round 3
// baseline (325.931 us; speedup 1.0000x reference)
//
#include <hip/hip_runtime.h>

// SSIM fused, round 3: 4 output cols/thread, all-ds_read_b128 LDS traffic,
// vertical RUNNING sums (V_q += t_new - t_old) with t_old recomputed from a
// 9-slot LDS input-row ring (bit-identical recompute -> exact cancellation).
// One barrier/row; 2-deep global prefetch via A/B reg double-buffer.
// Geometry: 16 x 1 x 1080 x 1920 fp32; VALID 7x7 -> 16 x 1074 x 1914.

constexpr int W_IN = 1920, H_IN = 1080;
constexpr int WOUT = W_IN - 6;    // 1914
constexpr int HOUT = H_IN - 6;    // 1074
constexpr int NBATCH = 16;
constexpr int TW = 1016;          // output cols per x-tile (254 threads x 4)
constexpr int TH = 64;            // output rows per y-tile
constexpr int NITER = TH + 6;     // 70 input rows consumed per tile
constexpr int SLOTW = 1024;       // floats per image per ring slot
constexpr int NSLOT = 9;          // ring slots (7 window + write-ahead 1 + WAR)
constexpr int NBX = 2, NBY = 17;  // 2*1016>=1914, 17*64>=1074
constexpr int NBLK = NBX * NBY * NBATCH;  // 544

constexpr float C1f = 6.5025f;    // (0.01*255)^2
constexpr float C2f = 58.5225f;   // (0.03*255)^2
constexpr float INV49 = 1.0f / 49.0f;

__global__ __launch_bounds__(256, 2)
void ssim_kernel(const float* __restrict__ img1, const float* __restrict__ img2,
                 double* __restrict__ partial) {
  const int t = threadIdx.x;
  const int x0 = blockIdx.x * TW;
  const int y0 = blockIdx.y * TH;
  const size_t ib = (size_t)blockIdx.z * (size_t)(H_IN * W_IN);
  const float* __restrict__ p1 = img1 + ib;
  const float* __restrict__ p2 = img2 + ib;

  // ring: [slot][img][col]; 9*2*1024*4 = 73728 B -> 2 blocks/CU
  __shared__ float sh[NSLOT][2][SLOTW];
  __shared__ float wsum[4];

  const int lc = 4 * t;                       // local col base
  const int gcol = min(x0 + lc, W_IN - 4);    // clamped global load col
  const int rdo = min(lc, SLOTW - 12);        // read base (needs +12 floats)
  const int ldso = lc;                        // LDS write offset (float4 #t)

  // column validity (junk from clamped loads only reaches masked outputs)
  const bool m0 = (lc + 0 < TW) && (x0 + lc + 0 < WOUT);
  const bool m1 = (lc + 1 < TW) && (x0 + lc + 1 < WOUT);
  const bool m2 = (lc + 2 < TW) && (x0 + lc + 2 < WOUT);
  const bool m3 = (lc + 3 < TW) && (x0 + lc + 3 < WOUT);

  // vertical running sums: 5 quantities x 4 cols, named scalars
  float V1_0 = 0.f, V1_1 = 0.f, V1_2 = 0.f, V1_3 = 0.f;
  float V2_0 = 0.f, V2_1 = 0.f, V2_2 = 0.f, V2_3 = 0.f;
  float V11_0 = 0.f, V11_1 = 0.f, V11_2 = 0.f, V11_3 = 0.f;
  float V22_0 = 0.f, V22_1 = 0.f, V22_2 = 0.f, V22_3 = 0.f;
  float V12_0 = 0.f, V12_1 = 0.f, V12_2 = 0.f, V12_3 = 0.f;
  float accv = 0.f;

  // prologue: row 0 -> slot 0; row 1 -> A; row 2 -> B (in flight)
  {
    const int gy = min(y0, H_IN - 1);
    const float4 a = *(const float4*)(p1 + (size_t)gy * W_IN + gcol);
    const float4 b = *(const float4*)(p2 + (size_t)gy * W_IN + gcol);
    *(float4*)&sh[0][0][ldso] = a;
    *(float4*)&sh[0][1][ldso] = b;
  }
  float4 Aa, Ab, Ba, Bb;
  {
    const int gy = min(y0 + 1, H_IN - 1);
    Aa = *(const float4*)(p1 + (size_t)gy * W_IN + gcol);
    Ab = *(const float4*)(p2 + (size_t)gy * W_IN + gcol);
  }
  {
    const int gy = min(y0 + 2, H_IN - 1);
    Ba = *(const float4*)(p1 + (size_t)gy * W_IN + gcol);
    Bb = *(const float4*)(p2 + (size_t)gy * W_IN + gcol);
  }

  int sw = 1, sn = 0, so = 2;          // slots: write(k+1), new(k), old(k+2)
  int gyld = min(y0 + 3, H_IN - 1);    // next row to prefetch (row k+3)
  int oy = y0;                         // output row for epilogue iters

#define ADV(x) x = ((x) == NSLOT - 1) ? 0 : (x) + 1

  // horizontal 7-tap sliding sums of one staged row; OP is += (new) / -= (old)
#define HPASS(SLOT, OP)                                                       \
  {                                                                           \
    const float* _pa = &sh[SLOT][0][rdo];                                     \
    const float* _pb = &sh[SLOT][1][rdo];                                     \
    const float4 _a0 = *(const float4*)(_pa);                                 \
    const float4 _a1 = *(const float4*)(_pa + 4);                             \
    const float4 _a2 = *(const float4*)(_pa + 8);                             \
    const float4 _b0 = *(const float4*)(_pb);                                 \
    const float4 _b1 = *(const float4*)(_pb + 4);                             \
    const float4 _b2 = *(const float4*)(_pb + 8);                             \
    float s;                                                                  \
    s = ((_a0.x + _a0.y) + (_a0.z + _a0.w)) + ((_a1.x + _a1.y) + _a1.z);      \
    V1_0 OP s;                                                                \
    s = s - _a0.x + _a1.w;  V1_1 OP s;                                        \
    s = s - _a0.y + _a2.x;  V1_2 OP s;                                        \
    s = s - _a0.z + _a2.y;  V1_3 OP s;                                        \
    s = ((_b0.x + _b0.y) + (_b0.z + _b0.w)) + ((_b1.x + _b1.y) + _b1.z);      \
    V2_0 OP s;                                                                \
    s = s - _b0.x + _b1.w;  V2_1 OP s;                                        \
    s = s - _b0.y + _b2.x;  V2_2 OP s;                                        \
    s = s - _b0.z + _b2.y;  V2_3 OP s;                                        \
    s = _a0.x * _a0.x;                                                        \
    s = fmaf(_a0.y, _a0.y, s); s = fmaf(_a0.z, _a0.z, s);                     \
    s = fmaf(_a0.w, _a0.w, s); s = fmaf(_a1.x, _a1.x, s);                     \
    s = fmaf(_a1.y, _a1.y, s); s = fmaf(_a1.z, _a1.z, s);                     \
    V11_0 OP s;                                                               \
    s = fmaf(-_a0.x, _a0.x, fmaf(_a1.w, _a1.w, s));  V11_1 OP s;              \
    s = fmaf(-_a0.y, _a0.y, fmaf(_a2.x, _a2.x, s));  V11_2 OP s;              \
    s = fmaf(-_a0.z, _a0.z, fmaf(_a2.y, _a2.y, s));  V11_3 OP s;              \
    s = _b0.x * _b0.x;                                                        \
    s = fmaf(_b0.y, _b0.y, s); s = fmaf(_b0.z, _b0.z, s);                     \
    s = fmaf(_b0.w, _b0.w, s); s = fmaf(_b1.x, _b1.x, s);                     \
    s = fmaf(_b1.y, _b1.y, s); s = fmaf(_b1.z, _b1.z, s);                     \
    V22_0 OP s;                                                               \
    s = fmaf(-_b0.x, _b0.x, fmaf(_b1.w, _b1.w, s));  V22_1 OP s;              \
    s = fmaf(-_b0.y, _b0.y, fmaf(_b2.x, _b2.x, s));  V22_2 OP s;              \
    s = fmaf(-_b0.z, _b0.z, fmaf(_b2.y, _b2.y, s));  V22_3 OP s;              \
    s = _a0.x * _b0.x;                                                        \
    s = fmaf(_a0.y, _b0.y, s); s = fmaf(_a0.z, _b0.z, s);                     \
    s = fmaf(_a0.w, _b0.w, s); s = fmaf(_a1.x, _b1.x, s);                     \
    s = fmaf(_a1.y, _b1.y, s); s = fmaf(_a1.z, _b1.z, s);                     \
    V12_0 OP s;                                                               \
    s = fmaf(-_a0.x, _b0.x, fmaf(_a1.w, _b1.w, s));  V12_1 OP s;              \
    s = fmaf(-_a0.y, _b0.y, fmaf(_a2.x, _b2.x, s));  V12_2 OP s;              \
    s = fmaf(-_a0.z, _b0.z, fmaf(_a2.y, _b2.y, s));  V12_3 OP s;              \
  }

#define EPI1(VA, VB, VAA, VBB, VAB, MASK)                                     \
  {                                                                           \
    const float mu1 = (VA) * INV49, mu2 = (VB) * INV49;                       \
    const float mu1s = mu1 * mu1, mu2s = mu2 * mu2, mu12 = mu1 * mu2;         \
    const float sg1 = fmaf((VAA), INV49, -mu1s);                              \
    const float sg2 = fmaf((VBB), INV49, -mu2s);                              \
    const float sg12 = fmaf((VAB), INV49, -mu12);                             \
    const float v1 = fmaf(2.f, sg12, C2f);                                    \
    const float v2 = sg1 + sg2 + C2f;                                         \
    const float num = fmaf(2.f, mu12, C1f) * v1;                              \
    const float den = (mu1s + mu2s + C1f) * v2;                               \
    const float ss = num * __builtin_amdgcn_rcpf(den);                        \
    accv += (MASK) ? ss : 0.f;                                                \
  }

  // one input row: stage row k+1 (in RA/RB), prefetch row k+3, slide V,
  // emit output row k-6.
#define BODY(RA, RB, DO_OLD, DO_EPI)                                          \
  {                                                                           \
    __syncthreads();                                                          \
    *(float4*)&sh[sw][0][ldso] = RA;                                          \
    *(float4*)&sh[sw][1][ldso] = RB;                                          \
    RA = *(const float4*)(p1 + (size_t)gyld * W_IN + gcol);                   \
    RB = *(const float4*)(p2 + (size_t)gyld * W_IN + gcol);                   \
    gyld = min(gyld + 1, H_IN - 1);                                           \
    HPASS(sn, +=)                                                             \
    if (DO_OLD) { HPASS(so, -=) }                                             \
    if (DO_EPI) {                                                             \
      if (oy < HOUT) {                                                        \
        EPI1(V1_0, V2_0, V11_0, V22_0, V12_0, m0)                             \
        EPI1(V1_1, V2_1, V11_1, V22_1, V12_1, m1)                             \
        EPI1(V1_2, V2_2, V11_2, V22_2, V12_2, m2)                             \
        EPI1(V1_3, V2_3, V11_3, V22_3, V12_3, m3)                             \
      }                                                                       \
      ++oy;                                                                   \
    }                                                                         \
    ADV(sw); ADV(sn); ADV(so);                                                \
  }

  // k = 0..5: warm-up (V accumulates rows 0..5)
  BODY(Aa, Ab, false, false)   // k=0
  BODY(Ba, Bb, false, false)   // k=1
  BODY(Aa, Ab, false, false)   // k=2
  BODY(Ba, Bb, false, false)   // k=3
  BODY(Aa, Ab, false, false)   // k=4
  BODY(Ba, Bb, false, false)   // k=5
  BODY(Aa, Ab, false, true)    // k=6: first output row (rows 0..6)
  BODY(Ba, Bb, true,  true)    // k=7: sliding begins
  for (int k = 8; k < NITER; k += 2) {
    BODY(Aa, Ab, true, true)
    BODY(Ba, Bb, true, true)
  }
#undef BODY
#undef HPASS
#undef EPI1
#undef ADV

  // block reduction: 64-wide shuffle -> LDS -> one double per block
#pragma unroll
  for (int off = 32; off > 0; off >>= 1) accv += __shfl_down(accv, off);
  if ((t & 63) == 0) wsum[t >> 6] = accv;
  __syncthreads();
  if (t == 0) {
    const int bid = blockIdx.x + NBX * (blockIdx.y + NBY * blockIdx.z);
    partial[bid] = (double)wsum[0] + (double)wsum[1] +
                   (double)wsum[2] + (double)wsum[3];
  }
}

__global__ __launch_bounds__(256)
void finalize_kernel(const double* __restrict__ partial,
                     float* __restrict__ out) {
  const int tid = threadIdx.x;
  double s = 0.0;
  for (int i = tid; i < NBLK; i += 256) s += partial[i];
#pragma unroll
  for (int off = 32; off > 0; off >>= 1) s += __shfl_down(s, off);
  __shared__ double ws[4];
  if ((tid & 63) == 0) ws[tid >> 6] = s;
  __syncthreads();
  if (tid == 0) {
    const double tot = ws[0] + ws[1] + ws[2] + ws[3];
    out[0] = (float)(tot / ((double)NBATCH * (double)HOUT * (double)WOUT));
  }
}

extern "C" void kernel_launch(void* const* d_in, const int* in_sizes, int n_in,
                              void* d_out, int out_size, void* d_ws, size_t ws_size,
                              hipStream_t stream) {
  const float* img1 = (const float*)d_in[0];
  const float* img2 = (const float*)d_in[1];
  // d_in[2] is the uniform 1/49 window -- baked into INV49.
  double* partial = (double*)d_ws;  // NBLK doubles, every slot written
  dim3 grid(NBX, NBY, NBATCH);      // 2 x 17 x 16 = 544 blocks
  hipLaunchKernelGGL(ssim_kernel, grid, dim3(256), 0, stream, img1, img2,
                     partial);
  hipLaunchKernelGGL(finalize_kernel, dim3(1), dim3(256), 0, stream, partial,
                     (float*)d_out);
}

// Round 4
// 312.551 us; speedup vs baseline: 1.0428x; 1.0428x over previous
//
#include <hip/hip_runtime.h>

// SSIM fused, round 4: 4 cols/thread, b128-only LDS, vertical running sums
// with the 7-row-old rowsums held in a THREAD-PRIVATE 140-VGPR static ring
// (unroll-by-7 keeps all indices static) -> single horizontal pass per row.
// LDS ring is just 2 raw-row slots (16.4 KB). Grid = 512 blocks = exactly
// 2/CU (round 3's 544-block straggler round cost ~40%).
// Geometry: 16 x 1 x 1080 x 1920 fp32; VALID 7x7 -> 16 x 1074 x 1914.

constexpr int W_IN = 1920, H_IN = 1080;
constexpr int WOUT = W_IN - 6;    // 1914
constexpr int HOUT = H_IN - 6;    // 1074
constexpr int NBATCH = 16;
constexpr int TW = 1016;          // output cols per x-tile (254 thr x 4)
constexpr int TH = 71;            // output rows per y-tile
constexpr int NITER = 77;         // input rows consumed = 7*11 groups
constexpr int SLOTW = 1024;       // floats per image per slot
constexpr int NBX = 2, NBY = 16;  // 2*1016>=1914, 16*71>=1074
constexpr int NBLK = NBX * NBY * NBATCH;  // 512 = 2 per CU exactly

constexpr float C1f = 6.5025f;    // (0.01*255)^2
constexpr float C2f = 58.5225f;   // (0.03*255)^2
constexpr float INV49 = 1.0f / 49.0f;

__global__ __launch_bounds__(256, 2)
void ssim_kernel(const float* __restrict__ img1, const float* __restrict__ img2,
                 double* __restrict__ partial) {
  const int t = threadIdx.x;
  const int x0 = blockIdx.x * TW;
  const int y0 = blockIdx.y * TH;
  const size_t ib = (size_t)blockIdx.z * (size_t)(H_IN * W_IN);
  const float* __restrict__ p1 = img1 + ib;
  const float* __restrict__ p2 = img2 + ib;

  __shared__ float sh[2][2][SLOTW];   // [slot][img][col] = 16384 B
  __shared__ float wsum[4];

  const int lc = 4 * t;
  const int gcol = min(x0 + lc, W_IN - 4);   // clamped global col (coalesced)
  const int rdo = min(lc, SLOTW - 12);       // LDS read base (+12 floats)

  const bool m0 = (lc + 0 < TW) && (x0 + lc + 0 < WOUT);
  const bool m1 = (lc + 1 < TW) && (x0 + lc + 1 < WOUT);
  const bool m2 = (lc + 2 < TW) && (x0 + lc + 2 < WOUT);
  const bool m3 = (lc + 3 < TW) && (x0 + lc + 3 < WOUT);

  // ---- thread-private rowsum ring: 5 quantities x 4 cols x 7 slots ----
#define DECLR(Q, C)                                                          \
  float R##Q##_##C##_0 = 0.f, R##Q##_##C##_1 = 0.f, R##Q##_##C##_2 = 0.f,    \
        R##Q##_##C##_3 = 0.f, R##Q##_##C##_4 = 0.f, R##Q##_##C##_5 = 0.f,    \
        R##Q##_##C##_6 = 0.f;
  DECLR(1, 0) DECLR(1, 1) DECLR(1, 2) DECLR(1, 3)
  DECLR(2, 0) DECLR(2, 1) DECLR(2, 2) DECLR(2, 3)
  DECLR(3, 0) DECLR(3, 1) DECLR(3, 2) DECLR(3, 3)   // 3 = a*a
  DECLR(4, 0) DECLR(4, 1) DECLR(4, 2) DECLR(4, 3)   // 4 = b*b
  DECLR(5, 0) DECLR(5, 1) DECLR(5, 2) DECLR(5, 3)   // 5 = a*b
#undef DECLR
#define DECLV(Q) float V##Q##_0 = 0.f, V##Q##_1 = 0.f, V##Q##_2 = 0.f, V##Q##_3 = 0.f;
  DECLV(1) DECLV(2) DECLV(3) DECLV(4) DECLV(5)
#undef DECLV

  float accv = 0.f;

  // prologue: row 0 -> slot 0; row 1 -> RA/RB (in flight)
  {
    const float4 a = *(const float4*)(p1 + (size_t)min(y0, H_IN - 1) * W_IN + gcol);
    const float4 b = *(const float4*)(p2 + (size_t)min(y0, H_IN - 1) * W_IN + gcol);
    *(float4*)&sh[0][0][lc] = a;
    *(float4*)&sh[0][1][lc] = b;
  }
  float4 RA = *(const float4*)(p1 + (size_t)min(y0 + 1, H_IN - 1) * W_IN + gcol);
  float4 RB = *(const float4*)(p2 + (size_t)min(y0 + 1, H_IN - 1) * W_IN + gcol);
  int gyld = min(y0 + 2, H_IN - 1);   // next row to load
  int oy = y0;                        // output row counter

  // ring update: V += s - R_old; R_old = s   (J is a literal 0..6)
#define QC(Q, C, J)                                                          \
  { V##Q##_##C += s - R##Q##_##C##_##J; R##Q##_##C##_##J = s; }

#define EPI1(VA, VB, VAA, VBB, VAB, MASK)                                    \
  {                                                                          \
    const float mu1 = (VA) * INV49, mu2 = (VB) * INV49;                      \
    const float mu1s = mu1 * mu1, mu2s = mu2 * mu2, mu12 = mu1 * mu2;        \
    const float sg1 = fmaf((VAA), INV49, -mu1s);                             \
    const float sg2 = fmaf((VBB), INV49, -mu2s);                             \
    const float sg12 = fmaf((VAB), INV49, -mu12);                            \
    const float v1 = fmaf(2.f, sg12, C2f);                                   \
    const float v2 = sg1 + sg2 + C2f;                                        \
    const float num = fmaf(2.f, mu12, C1f) * v1;                             \
    const float den = (mu1s + mu2s + C1f) * v2;                              \
    const float ss = num * __builtin_amdgcn_rcpf(den);                       \
    accv += (MASK) ? ss : 0.f;                                               \
  }

  // One input row k: barrier; stage row k+1 (RA/RB) -> slot WS; prefetch
  // row k+2; horizontal 7-tap sliding sums from slot RS; ring-slide V;
  // emit output row k-6 when DO_EPI.
#define STEP(J, WS, RS, DO_EPI)                                              \
  {                                                                          \
    __syncthreads();                                                         \
    *(float4*)&sh[WS][0][lc] = RA;                                           \
    *(float4*)&sh[WS][1][lc] = RB;                                           \
    RA = *(const float4*)(p1 + (size_t)gyld * W_IN + gcol);                  \
    RB = *(const float4*)(p2 + (size_t)gyld * W_IN + gcol);                  \
    gyld = min(gyld + 1, H_IN - 1);                                          \
    const float* _pa = &sh[RS][0][rdo];                                      \
    const float* _pb = &sh[RS][1][rdo];                                      \
    const float4 a0 = *(const float4*)(_pa);                                 \
    const float4 a1 = *(const float4*)(_pa + 4);                             \
    const float4 a2 = *(const float4*)(_pa + 8);                             \
    const float4 b0 = *(const float4*)(_pb);                                 \
    const float4 b1 = *(const float4*)(_pb + 4);                             \
    const float4 b2 = *(const float4*)(_pb + 8);                             \
    float s;                                                                 \
    s = ((a0.x + a0.y) + (a0.z + a0.w)) + ((a1.x + a1.y) + a1.z);            \
    QC(1, 0, J)                                                              \
    s = s - a0.x + a1.w;  QC(1, 1, J)                                        \
    s = s - a0.y + a2.x;  QC(1, 2, J)                                        \
    s = s - a0.z + a2.y;  QC(1, 3, J)                                        \
    s = ((b0.x + b0.y) + (b0.z + b0.w)) + ((b1.x + b1.y) + b1.z);            \
    QC(2, 0, J)                                                              \
    s = s - b0.x + b1.w;  QC(2, 1, J)                                        \
    s = s - b0.y + b2.x;  QC(2, 2, J)                                        \
    s = s - b0.z + b2.y;  QC(2, 3, J)                                        \
    s = a0.x * a0.x;                                                         \
    s = fmaf(a0.y, a0.y, s); s = fmaf(a0.z, a0.z, s);                        \
    s = fmaf(a0.w, a0.w, s); s = fmaf(a1.x, a1.x, s);                        \
    s = fmaf(a1.y, a1.y, s); s = fmaf(a1.z, a1.z, s);                        \
    QC(3, 0, J)                                                              \
    s = fmaf(-a0.x, a0.x, fmaf(a1.w, a1.w, s));  QC(3, 1, J)                 \
    s = fmaf(-a0.y, a0.y, fmaf(a2.x, a2.x, s));  QC(3, 2, J)                 \
    s = fmaf(-a0.z, a0.z, fmaf(a2.y, a2.y, s));  QC(3, 3, J)                 \
    s = b0.x * b0.x;                                                         \
    s = fmaf(b0.y, b0.y, s); s = fmaf(b0.z, b0.z, s);                        \
    s = fmaf(b0.w, b0.w, s); s = fmaf(b1.x, b1.x, s);                        \
    s = fmaf(b1.y, b1.y, s); s = fmaf(b1.z, b1.z, s);                        \
    QC(4, 0, J)                                                              \
    s = fmaf(-b0.x, b0.x, fmaf(b1.w, b1.w, s));  QC(4, 1, J)                 \
    s = fmaf(-b0.y, b0.y, fmaf(b2.x, b2.x, s));  QC(4, 2, J)                 \
    s = fmaf(-b0.z, b0.z, fmaf(b2.y, b2.y, s));  QC(4, 3, J)                 \
    s = a0.x * b0.x;                                                         \
    s = fmaf(a0.y, b0.y, s); s = fmaf(a0.z, b0.z, s);                        \
    s = fmaf(a0.w, b0.w, s); s = fmaf(a1.x, b1.x, s);                        \
    s = fmaf(a1.y, b1.y, s); s = fmaf(a1.z, b1.z, s);                        \
    QC(5, 0, J)                                                              \
    s = fmaf(-a0.x, b0.x, fmaf(a1.w, b1.w, s));  QC(5, 1, J)                 \
    s = fmaf(-a0.y, b0.y, fmaf(a2.x, b2.x, s));  QC(5, 2, J)                 \
    s = fmaf(-a0.z, b0.z, fmaf(a2.y, b2.y, s));  QC(5, 3, J)                 \
    if (DO_EPI) {                                                            \
      if (oy < HOUT) {                                                       \
        EPI1(V1_0, V2_0, V3_0, V4_0, V5_0, m0)                               \
        EPI1(V1_1, V2_1, V3_1, V4_1, V5_1, m1)                               \
        EPI1(V1_2, V2_2, V3_2, V4_2, V5_2, m2)                               \
        EPI1(V1_3, V2_3, V3_3, V4_3, V5_3, m3)                               \
      }                                                                      \
      ++oy;                                                                  \
    }                                                                        \
  }

  // group 0: rows 0..6 (slot parity: row k -> slot k&1)
  STEP(0, 1, 0, false) STEP(1, 0, 1, false) STEP(2, 1, 0, false)
  STEP(3, 0, 1, false) STEP(4, 1, 0, false) STEP(5, 0, 1, false)
  STEP(6, 1, 0, true)
  // 5 pairs of (odd-parity group, even-parity group): rows 7..76
  for (int gp = 0; gp < 5; ++gp) {
    STEP(0, 0, 1, true) STEP(1, 1, 0, true) STEP(2, 0, 1, true)
    STEP(3, 1, 0, true) STEP(4, 0, 1, true) STEP(5, 1, 0, true)
    STEP(6, 0, 1, true)
    STEP(0, 1, 0, true) STEP(1, 0, 1, true) STEP(2, 1, 0, true)
    STEP(3, 0, 1, true) STEP(4, 1, 0, true) STEP(5, 0, 1, true)
    STEP(6, 1, 0, true)
  }
#undef STEP
#undef QC
#undef EPI1

  // block reduction: 64-wide shuffle -> LDS -> one double per block
#pragma unroll
  for (int off = 32; off > 0; off >>= 1) accv += __shfl_down(accv, off);
  if ((t & 63) == 0) wsum[t >> 6] = accv;
  __syncthreads();
  if (t == 0) {
    const int bid = blockIdx.x + NBX * (blockIdx.y + NBY * blockIdx.z);
    partial[bid] = (double)wsum[0] + (double)wsum[1] +
                   (double)wsum[2] + (double)wsum[3];
  }
}

__global__ __launch_bounds__(256)
void finalize_kernel(const double* __restrict__ partial,
                     float* __restrict__ out) {
  const int tid = threadIdx.x;
  double s = 0.0;
  for (int i = tid; i < NBLK; i += 256) s += partial[i];
#pragma unroll
  for (int off = 32; off > 0; off >>= 1) s += __shfl_down(s, off);
  __shared__ double ws[4];
  if ((tid & 63) == 0) ws[tid >> 6] = s;
  __syncthreads();
  if (tid == 0) {
    const double tot = ws[0] + ws[1] + ws[2] + ws[3];
    out[0] = (float)(tot / ((double)NBATCH * (double)HOUT * (double)WOUT));
  }
}

extern "C" void kernel_launch(void* const* d_in, const int* in_sizes, int n_in,
                              void* d_out, int out_size, void* d_ws, size_t ws_size,
                              hipStream_t stream) {
  const float* img1 = (const float*)d_in[0];
  const float* img2 = (const float*)d_in[1];
  // d_in[2] is the uniform 1/49 window -- baked into INV49.
  double* partial = (double*)d_ws;  // NBLK doubles, every slot written
  dim3 grid(NBX, NBY, NBATCH);      // 2 x 16 x 16 = 512 blocks
  hipLaunchKernelGGL(ssim_kernel, grid, dim3(256), 0, stream, img1, img2,
                     partial);
  hipLaunchKernelGGL(finalize_kernel, dim3(1), dim3(256), 0, stream, partial,
                     (float*)d_out);
}

// Round 5
// 291.203 us; speedup vs baseline: 1.1193x; 1.0733x over previous
//
#include <hip/hip_runtime.h>

// SSIM fused, round 5: barrier-free wavefront design.
//  - Each lane loads the float4 (4 cols) of BOTH images for its columns.
//  - Horizontal 7-tap halo (6 neighbor floats/img) comes from the next two
//    lanes via ds_bpermute (intra-wave, no LDS arrays, NO __syncthreads in
//    the main loop) -> waves slip freely, global latency self-hides.
//  - Waves overlap by 3 lanes: 61/64 lanes productive (4.7% waste).
//  - Vertical 7-window: running sums V += s_new - s_old with the 7-row-old
//    rowsums in a 140-VGPR thread-private static ring (unroll-by-7).
//  - Round 4's spill cause: allocator heuristic chose 128 VGPRs + scratch.
//    amdgpu_waves_per_eu(2,2) pins target occupancy -> 256-VGPR budget.
// Geometry: 16 x 1 x 1080 x 1920 fp32; VALID 7x7 -> 16 x 1074 x 1914.

constexpr int W_IN = 1920, H_IN = 1080;
constexpr int WOUT = W_IN - 6;    // 1914
constexpr int HOUT = H_IN - 6;    // 1074
constexpr int NBATCH = 16;
constexpr int WCOLS = 244;        // productive cols per wave (61 lanes x 4)
constexpr int TW = 4 * WCOLS;     // 976 cols per block
constexpr int TH = 71;            // output rows per y-tile (NITER = 77 = 7*11)
constexpr int NBX = 2, NBY = 16;  // 2*976>=1914(+pad), 16*71>=1074
constexpr int NBLK = NBX * NBY * NBATCH;  // 512 = exactly 2 per CU

constexpr float C1f = 6.5025f;    // (0.01*255)^2
constexpr float C2f = 58.5225f;   // (0.03*255)^2
constexpr float INV49 = 1.0f / 49.0f;

__device__ __forceinline__ float bperm(int addr, float v) {
  return __int_as_float(__builtin_amdgcn_ds_bpermute(addr, __float_as_int(v)));
}

__global__ __attribute__((amdgpu_flat_work_group_size(256, 256),
                          amdgpu_waves_per_eu(2, 2)))
void ssim_kernel(const float* __restrict__ img1, const float* __restrict__ img2,
                 double* __restrict__ partial) {
  const int t = threadIdx.x;
  const int lane = t & 63;
  const int xw = blockIdx.x * TW + (t >> 6) * WCOLS;  // wave col base
  const int y0 = blockIdx.y * TH;
  const size_t ib = (size_t)blockIdx.z * (size_t)(H_IN * W_IN);
  const float* __restrict__ p1 = img1 + ib;
  const float* __restrict__ p2 = img2 + ib;

  const int gcol = min(xw + 4 * lane, W_IN - 4);  // clamped, 16B-aligned
  const int up1 = ((lane + 1) & 63) << 2;         // bpermute byte addrs
  const int up2 = ((lane + 2) & 63) << 2;
  const bool lv = lane < 61;
  const bool m0 = lv && (xw + 4 * lane + 0 < WOUT);
  const bool m1 = lv && (xw + 4 * lane + 1 < WOUT);
  const bool m2 = lv && (xw + 4 * lane + 2 < WOUT);
  const bool m3 = lv && (xw + 4 * lane + 3 < WOUT);

  // thread-private rowsum ring: 5 quantities x 4 cols x 7 slots (named)
#define DECLR(Q, C)                                                          \
  float R##Q##_##C##_0 = 0.f, R##Q##_##C##_1 = 0.f, R##Q##_##C##_2 = 0.f,    \
        R##Q##_##C##_3 = 0.f, R##Q##_##C##_4 = 0.f, R##Q##_##C##_5 = 0.f,    \
        R##Q##_##C##_6 = 0.f;
  DECLR(1, 0) DECLR(1, 1) DECLR(1, 2) DECLR(1, 3)
  DECLR(2, 0) DECLR(2, 1) DECLR(2, 2) DECLR(2, 3)
  DECLR(3, 0) DECLR(3, 1) DECLR(3, 2) DECLR(3, 3)   // 3 = a*a
  DECLR(4, 0) DECLR(4, 1) DECLR(4, 2) DECLR(4, 3)   // 4 = b*b
  DECLR(5, 0) DECLR(5, 1) DECLR(5, 2) DECLR(5, 3)   // 5 = a*b
#undef DECLR
#define DECLV(Q) float V##Q##_0 = 0.f, V##Q##_1 = 0.f, V##Q##_2 = 0.f, V##Q##_3 = 0.f;
  DECLV(1) DECLV(2) DECLV(3) DECLV(4) DECLV(5)
#undef DECLV

  float accv = 0.f;

  // prologue: row y0 -> A registers (y0 <= 1065, no clamp needed)
  float4 Aa = *(const float4*)(p1 + (size_t)y0 * W_IN + gcol);
  float4 Ab = *(const float4*)(p2 + (size_t)y0 * W_IN + gcol);
  float4 Ba, Bb;
  int gyn = y0 + 1;   // next input row to load (block-uniform -> SALU)
  int oy = y0;        // output row counter

#define QC(Q, C, J)                                                         \
  { V##Q##_##C += s - R##Q##_##C##_##J; R##Q##_##C##_##J = s; }

#define EPI1(VA, VB, VAA, VBB, VAB, MASK)                                   \
  {                                                                         \
    const float mu1 = (VA) * INV49, mu2 = (VB) * INV49;                     \
    const float mu1s = mu1 * mu1, mu2s = mu2 * mu2, mu12 = mu1 * mu2;       \
    const float sg1 = fmaf((VAA), INV49, -mu1s);                            \
    const float sg2 = fmaf((VBB), INV49, -mu2s);                            \
    const float sg12 = fmaf((VAB), INV49, -mu12);                           \
    const float v1 = fmaf(2.f, sg12, C2f);                                  \
    const float v2 = sg1 + sg2 + C2f;                                       \
    const float num = fmaf(2.f, mu12, C1f) * v1;                            \
    const float den = (mu1s + mu2s + C1f) * v2;                             \
    const float ss = num * __builtin_amdgcn_rcpf(den);                      \
    accv += (MASK) ? ss : 0.f;                                              \
  }

  // One input row k: CA holds row k (both imgs); NA receives row k+1
  // (issued first for latency cover); halo via bpermute; ring-slide; EPI.
#define STEP(J, CAa, CAb, NAa, NAb, DO_EPI)                                 \
  {                                                                         \
    NAa = *(const float4*)(p1 + (size_t)gyn * W_IN + gcol);                 \
    NAb = *(const float4*)(p2 + (size_t)gyn * W_IN + gcol);                 \
    gyn = min(gyn + 1, H_IN - 1);                                           \
    const float a1x = bperm(up1, CAa.x), a1y = bperm(up1, CAa.y);           \
    const float a1z = bperm(up1, CAa.z), a1w = bperm(up1, CAa.w);           \
    const float a2x = bperm(up2, CAa.x), a2y = bperm(up2, CAa.y);           \
    const float b1x = bperm(up1, CAb.x), b1y = bperm(up1, CAb.y);           \
    const float b1z = bperm(up1, CAb.z), b1w = bperm(up1, CAb.w);           \
    const float b2x = bperm(up2, CAb.x), b2y = bperm(up2, CAb.y);           \
    float s;                                                                \
    s = ((CAa.x + CAa.y) + (CAa.z + CAa.w)) + ((a1x + a1y) + a1z);          \
    QC(1, 0, J)                                                             \
    s = s - CAa.x + a1w;  QC(1, 1, J)                                       \
    s = s - CAa.y + a2x;  QC(1, 2, J)                                       \
    s = s - CAa.z + a2y;  QC(1, 3, J)                                       \
    s = ((CAb.x + CAb.y) + (CAb.z + CAb.w)) + ((b1x + b1y) + b1z);          \
    QC(2, 0, J)                                                             \
    s = s - CAb.x + b1w;  QC(2, 1, J)                                       \
    s = s - CAb.y + b2x;  QC(2, 2, J)                                       \
    s = s - CAb.z + b2y;  QC(2, 3, J)                                       \
    s = CAa.x * CAa.x;                                                      \
    s = fmaf(CAa.y, CAa.y, s); s = fmaf(CAa.z, CAa.z, s);                   \
    s = fmaf(CAa.w, CAa.w, s); s = fmaf(a1x, a1x, s);                       \
    s = fmaf(a1y, a1y, s); s = fmaf(a1z, a1z, s);                           \
    QC(3, 0, J)                                                             \
    s = fmaf(-CAa.x, CAa.x, fmaf(a1w, a1w, s));  QC(3, 1, J)                \
    s = fmaf(-CAa.y, CAa.y, fmaf(a2x, a2x, s));  QC(3, 2, J)                \
    s = fmaf(-CAa.z, CAa.z, fmaf(a2y, a2y, s));  QC(3, 3, J)                \
    s = CAb.x * CAb.x;                                                      \
    s = fmaf(CAb.y, CAb.y, s); s = fmaf(CAb.z, CAb.z, s);                   \
    s = fmaf(CAb.w, CAb.w, s); s = fmaf(b1x, b1x, s);                       \
    s = fmaf(b1y, b1y, s); s = fmaf(b1z, b1z, s);                           \
    QC(4, 0, J)                                                             \
    s = fmaf(-CAb.x, CAb.x, fmaf(b1w, b1w, s));  QC(4, 1, J)                \
    s = fmaf(-CAb.y, CAb.y, fmaf(b2x, b2x, s));  QC(4, 2, J)                \
    s = fmaf(-CAb.z, CAb.z, fmaf(b2y, b2y, s));  QC(4, 3, J)                \
    s = CAa.x * CAb.x;                                                      \
    s = fmaf(CAa.y, CAb.y, s); s = fmaf(CAa.z, CAb.z, s);                   \
    s = fmaf(CAa.w, CAb.w, s); s = fmaf(a1x, b1x, s);                       \
    s = fmaf(a1y, b1y, s); s = fmaf(a1z, b1z, s);                           \
    QC(5, 0, J)                                                             \
    s = fmaf(-CAa.x, CAb.x, fmaf(a1w, b1w, s));  QC(5, 1, J)                \
    s = fmaf(-CAa.y, CAb.y, fmaf(a2x, b2x, s));  QC(5, 2, J)                \
    s = fmaf(-CAa.z, CAb.z, fmaf(a2y, b2y, s));  QC(5, 3, J)                \
    if (DO_EPI) {                                                           \
      if (oy < HOUT) {                                                      \
        EPI1(V1_0, V2_0, V3_0, V4_0, V5_0, m0)                              \
        EPI1(V1_1, V2_1, V3_1, V4_1, V5_1, m1)                              \
        EPI1(V1_2, V2_2, V3_2, V4_2, V5_2, m2)                              \
        EPI1(V1_3, V2_3, V3_3, V4_3, V5_3, m3)                              \
      }                                                                     \
      ++oy;                                                                 \
    }                                                                       \
  }

  // warm-up group: rows 0..6 (row k consumed from A if k even, B if odd)
  STEP(0, Aa, Ab, Ba, Bb, false)
  STEP(1, Ba, Bb, Aa, Ab, false)
  STEP(2, Aa, Ab, Ba, Bb, false)
  STEP(3, Ba, Bb, Aa, Ab, false)
  STEP(4, Aa, Ab, Ba, Bb, false)
  STEP(5, Ba, Bb, Aa, Ab, false)
  STEP(6, Aa, Ab, Ba, Bb, true)
  // 5 x (odd-start group + even-start group): rows 7..76
  for (int gp = 0; gp < 5; ++gp) {
    STEP(0, Ba, Bb, Aa, Ab, true)
    STEP(1, Aa, Ab, Ba, Bb, true)
    STEP(2, Ba, Bb, Aa, Ab, true)
    STEP(3, Aa, Ab, Ba, Bb, true)
    STEP(4, Ba, Bb, Aa, Ab, true)
    STEP(5, Aa, Ab, Ba, Bb, true)
    STEP(6, Ba, Bb, Aa, Ab, true)
    STEP(0, Aa, Ab, Ba, Bb, true)
    STEP(1, Ba, Bb, Aa, Ab, true)
    STEP(2, Aa, Ab, Ba, Bb, true)
    STEP(3, Ba, Bb, Aa, Ab, true)
    STEP(4, Aa, Ab, Ba, Bb, true)
    STEP(5, Ba, Bb, Aa, Ab, true)
    STEP(6, Aa, Ab, Ba, Bb, true)
  }
#undef STEP
#undef QC
#undef EPI1

  // block reduction: 64-wide shuffle -> LDS -> one double per block
  __shared__ float wsum[4];
#pragma unroll
  for (int off = 32; off > 0; off >>= 1) accv += __shfl_down(accv, off);
  if ((t & 63) == 0) wsum[t >> 6] = accv;
  __syncthreads();
  if (t == 0) {
    const int bid = blockIdx.x + NBX * (blockIdx.y + NBY * blockIdx.z);
    partial[bid] = (double)wsum[0] + (double)wsum[1] +
                   (double)wsum[2] + (double)wsum[3];
  }
}

__global__ __launch_bounds__(256)
void finalize_kernel(const double* __restrict__ partial,
                     float* __restrict__ out) {
  const int tid = threadIdx.x;
  double s = 0.0;
  for (int i = tid; i < NBLK; i += 256) s += partial[i];
#pragma unroll
  for (int off = 32; off > 0; off >>= 1) s += __shfl_down(s, off);
  __shared__ double ws[4];
  if ((tid & 63) == 0) ws[tid >> 6] = s;
  __syncthreads();
  if (tid == 0) {
    const double tot = ws[0] + ws[1] + ws[2] + ws[3];
    out[0] = (float)(tot / ((double)NBATCH * (double)HOUT * (double)WOUT));
  }
}

extern "C" void kernel_launch(void* const* d_in, const int* in_sizes, int n_in,
                              void* d_out, int out_size, void* d_ws, size_t ws_size,
                              hipStream_t stream) {
  const float* img1 = (const float*)d_in[0];
  const float* img2 = (const float*)d_in[1];
  // d_in[2] is the uniform 1/49 window -- baked into INV49.
  double* partial = (double*)d_ws;  // NBLK doubles, every slot written
  dim3 grid(NBX, NBY, NBATCH);      // 2 x 16 x 16 = 512 blocks
  hipLaunchKernelGGL(ssim_kernel, grid, dim3(256), 0, stream, img1, img2,
                     partial);
  hipLaunchKernelGGL(finalize_kernel, dim3(1), dim3(256), 0, stream, partial,
                     (float*)d_out);
}